// Round 1
// 259.501 us; speedup vs baseline: 1.0170x; 1.0170x over previous
//
#include <hip/hip_runtime.h>

// GGNN message passing, round 4: fused-direction, double-buffered main kernel.
//
//   adj in {0..3}. Planes: B0 = bit0(adj), B1 = bit1(adj), T = B0&B1.
//   P0 = B0@H, P1 = B1@H, PT = T@H, PA[e] = sum_j h[j][e]  (per batch)
//   m_in  = P0(M1-M0)^T + P1(M2-M0)^T + PT(M0-M1-M2+M3)^T + (bias + PA M0^T)
//   (out-direction: same with adj^T and Mout.)
//
// Round-4 changes vs round 3 (262 us):
//  * ggnn_main fuses dir=0/1 into one block (512 blocks): B-fragments are
//    shared, so 4 LDS b128 reads feed 24 MFMA (was 12) and Hws L2 traffic
//    halves (128->64 MB).
//  * jc loop is double-buffered (80 KB LDS, 2 blocks/CU): stage jc+1 issued
//    BEFORE compute jc, single barrier per chunk -> vmcnt(0) drain overlaps
//    ~6400 cy of compute instead of stalling.
//  * prep_h fused into pack_adj dispatch (independent work, concurrent);
//    PA atomics + memset replaced by race-free per-thread partials reduced
//    in prep_m. 5 dispatches -> 3.
//
// Model: pack+prep ~25 us (128 MB adj read-bound), prep_m ~3, main ~15
// (MFMA-pipe floor 12.4 us), graph ~8 -> ~50 us of kernel time. Top-5
// counters show only harness 512 MiB poison fills (80 us @ 84-86% HBM peak);
// if dur_us stays ~255-262 the measurement is fill-dominated -> roofline.

namespace {

typedef unsigned int  u32;
typedef unsigned short u16;
typedef __attribute__((ext_vector_type(8))) short bf16x8;
typedef __attribute__((ext_vector_type(4))) float f32x4;

constexpr int NN = 1024;
constexpr int ND = 64;

__device__ inline u16 f2bf(float x) {                  // f32 -> bf16 bits, RNE
    u32 u = __float_as_uint(x);
    return (u16)((u + 0x7FFFu + ((u >> 16) & 1u)) >> 16);
}
__device__ inline float bf2f(u16 x) { return __uint_as_float(((u32)x) << 16); }

#if defined(__has_builtin)
#if __has_builtin(__builtin_amdgcn_global_load_lds)
#define HAVE_GLL 1
#endif
#endif

__device__ inline void async_copy16(const void* g, void* l) {
    // g is per-lane (base + lane*16); HW writes LDS at (uniform l) + lane*16.
#ifdef HAVE_GLL
    typedef __attribute__((address_space(1))) const u32 gu32;
    typedef __attribute__((address_space(3))) u32 lu32;
    __builtin_amdgcn_global_load_lds((gu32*)g, (lu32*)l, 16, 0, 0);
#else
    int lane = threadIdx.x & 63;
    ((uint4*)l)[lane] = *(const uint4*)((const char*)g);
#endif
}

// ------------------------------------------------- K1: pack_adj + prep_h
// bid < 2048: pack block (b, It, Jt, s): adj rows It*256+s*64..+64,
//   cols Jt*256..+256 -> adjP row-packs + adjPT col-packs (2-bit).
// bid >= 2048: prep_h block (b, jc): h -> Hws bf16 H^T tiles
//   [b][jc][u(j-octet)][e] + PApart[(b*4+jc)*256 + tq*64 + e] partial sums.
__global__ __launch_bounds__(256) void pack_and_preph(
    const int* __restrict__ adj, u32* __restrict__ adjP, u32* __restrict__ adjPT,
    const float* __restrict__ h, u16* __restrict__ Hws, float* __restrict__ PApart)
{
    __shared__ __align__(16) char sm1[36864];   // overlay: rp (4 KB) / hl (36 KB)
    const int t = threadIdx.x;
    const int bid = blockIdx.x;

    if (bid < 2048) {
        u32 (*rp)[16] = (u32(*)[16])sm1;        // [row][16 u32]
        const int b = bid >> 6, It = (bid >> 4) & 3, Jt = (bid >> 2) & 3, s = bid & 3;
        const int* base = adj + ((size_t)b << 20) + (size_t)(It * 256 + s * 64) * NN + Jt * 256;

        const int row = t >> 2, seg = t & 3;
        const int* rptr = base + (size_t)row * NN + seg * 64;
        u32 w[4];
        #pragma unroll
        for (int q = 0; q < 4; ++q) {
            int4 v0 = *(const int4*)(rptr + q * 16 + 0);
            int4 v1 = *(const int4*)(rptr + q * 16 + 4);
            int4 v2 = *(const int4*)(rptr + q * 16 + 8);
            int4 v3 = *(const int4*)(rptr + q * 16 + 12);
            u32 u = (u32)(v0.x & 3) | ((u32)(v0.y & 3) << 2) | ((u32)(v0.z & 3) << 4) | ((u32)(v0.w & 3) << 6)
                  | ((u32)(v1.x & 3) << 8) | ((u32)(v1.y & 3) << 10) | ((u32)(v1.z & 3) << 12) | ((u32)(v1.w & 3) << 14)
                  | ((u32)(v2.x & 3) << 16) | ((u32)(v2.y & 3) << 18) | ((u32)(v2.z & 3) << 20) | ((u32)(v2.w & 3) << 22)
                  | ((u32)(v3.x & 3) << 24) | ((u32)(v3.y & 3) << 26) | ((u32)(v3.z & 3) << 28) | ((u32)(v3.w & 3) << 30);
            w[q] = u;
        }
        u32* op = adjP + (((((size_t)b * 4 + Jt) * 16 + It * 4 + s) * 4 + seg) * 64 + row) * 4;
        *(uint4*)op = make_uint4(w[0], w[1], w[2], w[3]);
        *(uint4*)&rp[row][seg * 4] = make_uint4(w[0], w[1], w[2], w[3]);
        __syncthreads();

        const int sc = t >> 6, il = t & 63;
        const int cw = sc * 4 + (il >> 4);
        const int bp = (il & 15) * 2;
        u32 o[4];
        #pragma unroll
        for (int jj = 0; jj < 4; ++jj) {
            u32 acc = 0;
            #pragma unroll
            for (int k = 0; k < 16; ++k)
                acc |= ((rp[jj * 16 + k][cw] >> bp) & 3u) << (2 * k);
            o[jj] = acc;
        }
        u32* op2 = adjPT + (((((size_t)b * 4 + It) * 16 + Jt * 4 + sc) * 4 + s) * 64 + il) * 4;
        *(uint4*)op2 = make_uint4(o[0], o[1], o[2], o[3]);
    } else {
        u16 (*hl)[72] = (u16(*)[72])sm1;        // [256][72]
        const int pb = bid - 2048;
        const int b = pb >> 2, jc = pb & 3;
        const float* hb = h + ((size_t)b * NN + jc * 256) * ND;
        #pragma unroll
        for (int k = 0; k < 16; ++k) {
            int j = k * 16 + (t >> 4);
            int e4 = (t & 15) * 4;
            float4 v = *(const float4*)(hb + (size_t)j * ND + e4);
            *(u32*)&hl[j][e4]     = (u32)f2bf(v.x) | ((u32)f2bf(v.y) << 16);
            *(u32*)&hl[j][e4 + 2] = (u32)f2bf(v.z) | ((u32)f2bf(v.w) << 16);
        }
        __syncthreads();
        u16* ob = Hws + (size_t)(b * 4 + jc) * 2048 * 8;
        const int e = t & 63;
        float psum = 0.f;
        #pragma unroll
        for (int k = 0; k < 8; ++k) {
            int u = k * 4 + (t >> 6);
            u32 p0, p1, p2, p3;
            u16 x0 = hl[u * 8 + 0][e], x1 = hl[u * 8 + 1][e], x2 = hl[u * 8 + 2][e], x3 = hl[u * 8 + 3][e];
            u16 x4 = hl[u * 8 + 4][e], x5 = hl[u * 8 + 5][e], x6 = hl[u * 8 + 6][e], x7 = hl[u * 8 + 7][e];
            psum += bf2f(x0) + bf2f(x1) + bf2f(x2) + bf2f(x3) + bf2f(x4) + bf2f(x5) + bf2f(x6) + bf2f(x7);
            p0 = (u32)x0 | ((u32)x1 << 16); p1 = (u32)x2 | ((u32)x3 << 16);
            p2 = (u32)x4 | ((u32)x5 << 16); p3 = (u32)x6 | ((u32)x7 << 16);
            *(uint4*)(ob + (size_t)(u * 64 + e) * 8) = make_uint4(p0, p1, p2, p3);
        }
        // race-free partial: 16 partials per (b,e) = 4 jc x 4 thread-quads
        PApart[(size_t)(b * 4 + jc) * 256 + (t >> 6) * 64 + e] = psum;
    }
}

// ---------------------------------------------------------------- K2: prep_m
// Mws[dir][plane][d][e] bf16: plane0 = M1-M0, plane1 = M2-M0, plane2 = M0-M1-M2+M3.
// basews[b][dir][d] = bias[dir*64+d] + sum_e PA[b][e] * M{dir}[0][d][e],
// with PA[b][e] reduced from the 16 PApart partials.
__global__ __launch_bounds__(256) void prep_m(
    const float* __restrict__ Min, const float* __restrict__ Mout,
    const float* __restrict__ bias, const float* __restrict__ PApart,
    u16* __restrict__ Mws, float* __restrict__ basews)
{
    __shared__ float PAb[64];
    const int t = threadIdx.x, bb = blockIdx.x;
    if (t < 64) {
        float s = 0.f;
        #pragma unroll
        for (int q = 0; q < 16; ++q) s += PApart[(size_t)bb * 1024 + q * 64 + t];
        PAb[t] = s;
    }
    if (bb == 0) {
        for (int i = t; i < 2 * 4096; i += 256) {
            const float* M = (i < 4096) ? Min : Mout;
            int idx = i & 4095;
            float m0 = M[idx], m1 = M[4096 + idx], m2 = M[8192 + idx], m3 = M[12288 + idx];
            u16* o = Mws + (size_t)(i >> 12) * 3 * 4096;
            o[idx]            = f2bf(m1 - m0);
            o[4096 + idx]     = f2bf(m2 - m0);
            o[8192 + idx]     = f2bf(m0 - m1 - m2 + m3);
        }
    }
    __syncthreads();
    if (t < 128) {
        int d = t & 63, dir = t >> 6;
        const float* M0 = (dir ? Mout : Min) + d * 64;
        float s = bias[dir * 64 + d];
        #pragma unroll 8
        for (int e = 0; e < 64; ++e) s += PAb[e] * M0[e];
        basews[(bb * 2 + dir) * 64 + d] = s;
    }
}

// ---------------------------------------------------------------- K3: main
// 512 blocks (b, it), both directions per block, double-buffered jc pipeline.
// LDS: hL[2] 32 KB each @ 0/32768; adj[2 buf][2 dir] 4 KB each @ 65536.
__global__ __launch_bounds__(256, 2) void ggnn_main(
    const u32* __restrict__ adjP, const u32* __restrict__ adjPT,
    const u16* __restrict__ Hws, const u16* __restrict__ Mws,
    const float* __restrict__ basews, float* __restrict__ out)
{
    __shared__ __align__(16) char smem[81920];
    u16 (*Sb)[16][72] = (u16(*)[16][72])smem;   // epilogue overlay (24 slots, 55 KB)

    const int t = threadIdx.x;
    const int w = t >> 6, lane = t & 63;
    const int ln = t & 15, qd = (t & 63) >> 4, qd2 = qd >> 1;
    const int shamt = (qd & 1) * 16;
    const int bid = blockIdx.x;
    const int b = bid >> 4, it = bid & 15;

    f32x4 acc[2][3][4];
    #pragma unroll
    for (int d = 0; d < 2; ++d)
        #pragma unroll
        for (int p = 0; p < 3; ++p)
            #pragma unroll
            for (int nt = 0; nt < 4; ++nt) acc[d][p][nt] = (f32x4){0.f, 0.f, 0.f, 0.f};

    auto stage = [&](int buf, int jc) {
        char* hL = smem + buf * 32768;
        char* aL = smem + 65536 + buf * 8192;
        const char* ht = (const char*)(Hws + (size_t)(b * 4 + jc) * 16384);
        #pragma unroll
        for (int k = 0; k < 8; ++k) {
            int i = k * 4 + w;
            async_copy16(ht + i * 1024 + lane * 16, hL + i * 1024);
        }
        if (w < 2) {                      // wave 0: adjP tile, wave 1: adjPT tile
            const u32* Ad = w ? adjPT : adjP;
            const char* at = (const char*)(Ad + (size_t)((b * 4 + jc) * 16 + it) * 1024);
            #pragma unroll
            for (int u = 0; u < 4; ++u)
                async_copy16(at + u * 1024 + lane * 16, aL + w * 4096 + u * 1024);
        }
    };

    stage(0, 0);
    __syncthreads();                      // drains vmcnt(0): buf0 ready

    int buf = 0;
    for (int jc = 0; jc < 4; ++jc) {
        if (jc < 3) stage(buf ^ 1, jc + 1);   // issue next chunk, no wait

        const char* hL = smem + buf * 32768;
        const char* aL = smem + 65536 + buf * 8192;
        uint4 Ar[2][4];
        #pragma unroll
        for (int d = 0; d < 2; ++d)
            #pragma unroll
            for (int u = 0; u < 4; ++u)
                Ar[d][u] = *(const uint4*)(aL + d * 4096 + (u * 64 + w * 16 + ln) * 16);

        #pragma unroll
        for (int ks = 0; ks < 8; ++ks) {
            bf16x8 bf[4];                 // shared B-fragments: feed both dirs
            #pragma unroll
            for (int nt = 0; nt < 4; ++nt)
                bf[nt] = *(const bf16x8*)(hL + ((ks * 4 + qd) * 64 + nt * 16 + ln) * 16);
            #pragma unroll
            for (int d = 0; d < 2; ++d) {
                uint4 Q = Ar[d][ks >> 1];
                u32 a = (ks & 1) ? (qd2 ? Q.w : Q.z) : (qd2 ? Q.y : Q.x);
                u32 f  = (a >> shamt) & 0xFFFFu;
                u32 x0 = f & 0x5555u;
                u32 x1 = (f >> 1) & 0x5555u;
                u32 xt = x0 & x1;
                #pragma unroll
                for (int p = 0; p < 3; ++p) {
                    u32 xp = (p == 0) ? x0 : (p == 1) ? x1 : xt;
                    union { u32 u[4]; bf16x8 v; } A;
                    #pragma unroll
                    for (int wd = 0; wd < 4; ++wd) {
                        u32 z = xp >> (4 * wd);
                        A.u[wd] = ((z & 1u) | ((z & 4u) << 14)) * 0x3F80u;
                    }
                    #pragma unroll
                    for (int nt = 0; nt < 4; ++nt)
                        acc[d][p][nt] = __builtin_amdgcn_mfma_f32_16x16x32_bf16(
                            A.v, bf[nt], acc[d][p][nt], 0, 0, 0);
                }
            }
        }
        __syncthreads();   // next-chunk stage landed; all reads of buf done
        buf ^= 1;
    }

    // last-iteration barrier already separates LDS reads from Sb overlay
    #pragma unroll
    for (int d = 0; d < 2; ++d)
        #pragma unroll
        for (int p = 0; p < 3; ++p)
            #pragma unroll
            for (int nt = 0; nt < 4; ++nt)
                #pragma unroll
                for (int r = 0; r < 4; ++r)
                    Sb[(w * 2 + d) * 3 + p][qd * 4 + r][nt * 16 + ln] = f2bf(acc[d][p][nt][r]);
    // each wave reads only its own slots -> lgkmcnt ordering suffices

    #pragma unroll
    for (int d = 0; d < 2; ++d) {
        const float* bv = basews + (b * 2 + d) * 64;
        f32x4 acc2[4];
        #pragma unroll
        for (int dt = 0; dt < 4; ++dt) {
            float v = bv[dt * 16 + ln];
            acc2[dt] = (f32x4){v, v, v, v};
        }
        const u16* Mb = Mws + (size_t)d * 3 * 4096;
        #pragma unroll
        for (int p = 0; p < 3; ++p) {
            #pragma unroll
            for (int ks2 = 0; ks2 < 2; ++ks2) {
                bf16x8 af = *(const bf16x8*)&Sb[(w * 2 + d) * 3 + p][ln][ks2 * 32 + qd * 8];
                #pragma unroll
                for (int dt = 0; dt < 4; ++dt) {
                    bf16x8 mf = *(const bf16x8*)(Mb + (size_t)(p * 64 + dt * 16 + ln) * 64
                                                 + ks2 * 32 + qd * 8);
                    acc2[dt] = __builtin_amdgcn_mfma_f32_16x16x32_bf16(af, mf, acc2[dt], 0, 0, 0);
                }
            }
        }
        #pragma unroll
        for (int dt = 0; dt < 4; ++dt)
            #pragma unroll
            for (int r = 0; r < 4; ++r)
                out[((size_t)b * NN + it * 64 + w * 16 + qd * 4 + r) * 128
                    + d * 64 + dt * 16 + ln] = acc2[dt][r];
    }
}

} // namespace

extern "C" void kernel_launch(void* const* d_in, const int* in_sizes, int n_in,
                              void* d_out, int out_size, void* d_ws, size_t ws_size,
                              hipStream_t stream) {
    (void)in_sizes; (void)n_in; (void)out_size; (void)ws_size;
    const float* h    = (const float*)d_in[0];   // [32,1024,64] f32
    const int*   adj  = (const int*)d_in[1];     // [32,1024,1024] i32
    const float* Min  = (const float*)d_in[2];   // [4,64,64] f32
    const float* Mout = (const float*)d_in[3];   // [4,64,64] f32
    const float* bias = (const float*)d_in[4];   // [128] f32
    float* out = (float*)d_out;                  // [32,1024,128] f32

    char* ws = (char*)d_ws;
    u32* adjP     = (u32*)(ws + 0);              // 8 MB
    u32* adjPT    = (u32*)(ws + 8388608);        // 8 MB
    u16* Hws      = (u16*)(ws + 16777216);       // 4 MB
    float* PApart = (float*)(ws + 20971520);     // 128 KB
    u16* Mws      = (u16*)(ws + 21102592);       // 48 KB
    float* basews = (float*)(ws + 21151744);     // 16 KB

    pack_and_preph<<<2176, 256, 0, stream>>>(adj, adjP, adjPT, h, Hws, PApart);
    prep_m<<<32, 256, 0, stream>>>(Min, Mout, bias, PApart, Mws, basews);
    ggnn_main<<<512, 256, 0, stream>>>(adjP, adjPT, Hws, Mws, basews, out);
}